// Round 6
// baseline (1335.796 us; speedup 1.0000x reference)
//
#include <hip/hip_runtime.h>

// HierarchicalLTI2: 32-layer cascade of 64-dim LTI blocks, T=8192.
// Per-layer FIR truncation at J=16 taps; layer = GEMM (M=8192,N=64,K=1024)
// via implicit im2col, f16 MFMA fp32-acc. Taps built in fp32 by log-doubling.
// R6: systolic persistent megakernel over the (layer, time) wavefront.
//   - grid 256 WGs = 32 layers x 8 time-slices; all co-resident (1-2 WG/CU).
//   - each WG preloads its layer's full FIR bank B into 128 VGPRs (once).
//   - 32 chunks of 256 timesteps; producer->consumer handoff via device-scope
//     release/acquire counters (cnt[layer][chunk]==8) + __threadfence.
//   - chunk body = R3's verified stage_conv math.

#define LYR 32
#define NO  64
#define TSEQ 8192
#define JT  16
#define KD  (JT*NO)               // 1024
#define PROWS (TSEQ+JT)           // 8208
#define PBUF ((size_t)PROWS*NO)   // 525312 elements (f16)
#define CHUNK 256
#define NCH (TSEQ/CHUNK)          // 32

typedef _Float16 h16;
typedef _Float16 h16x8 __attribute__((ext_vector_type(8)));
typedef float    f32x4 __attribute__((ext_vector_type(4)));

// ---- prep1: zero pads (all 33 buffers) + cnt, cast u + C, seed K_0 ---------
__global__ __launch_bounds__(256) void prep1(
    const float* __restrict__ u, const float* __restrict__ B0,
    const float* __restrict__ Bl, const float* __restrict__ Cst,
    h16* __restrict__ pall, h16* __restrict__ ccast, float* __restrict__ kf32,
    int* __restrict__ cnt)
{
    int idx = blockIdx.x*256 + threadIdx.x;
    const int n_pad0 = JT*NO;            // 1024
    const int n_u    = TSEQ*NO;          // 524288
    const int n_c    = LYR*NO*NO;        // 131072
    const int n_k    = LYR*NO*NO;        // 131072
    const int n_zp   = 32*JT*NO;         // 32768 (pads of buffers 1..32)
    const int n_cnt  = LYR*NCH;          // 1024
    int total = n_pad0 + n_u + n_c + n_k + n_zp + n_cnt;
    for (; idx < total; idx += gridDim.x*256) {
        int e = idx;
        if (e < n_pad0) { pall[e] = (h16)0.f; continue; }
        e -= n_pad0;
        if (e < n_u) { pall[n_pad0 + e] = (h16)u[e]; continue; }
        e -= n_u;
        if (e < n_c) { ccast[e] = (h16)Cst[e]; continue; }
        e -= n_c;
        if (e < n_k) {
            int i = e >> 12;
            int r = e & 4095;
            kf32[((size_t)i*JT)*4096 + r] = (i == 0) ? B0[r] : Bl[e - 4096];
            continue;
        }
        e -= n_k;
        if (e < n_zp) {
            int b = e >> 10;             // 0..31 -> buffer b+1
            int off = e & 1023;
            pall[(size_t)(b+1)*PBUF + off] = (h16)0.f;
            continue;
        }
        e -= n_zp;
        cnt[e] = 0;
    }
}

// ---- build_step: K_{h+q} = A^h * K_q ; A^{2h} = A^h * A^h (s=0..3) ---------
__global__ __launch_bounds__(256) void build_step(
    const float* __restrict__ A_stack, float* __restrict__ kf32,
    float* __restrict__ apow, int s)
{
    int h = 1 << s;
    int extra = (s < 3) ? 1 : 0;
    int slots = h + extra;
    int layer = blockIdx.x / slots;
    int q     = blockIdx.x % slots;
    const float* X = (s == 0) ? (A_stack + (size_t)layer*4096)
                              : (apow + ((size_t)layer*4 + (s-1))*4096);
    const float* Yop;
    float* Z;
    if (q < h) { Yop = kf32 + ((size_t)layer*JT + q)*4096;
                 Z   = kf32 + ((size_t)layer*JT + h + q)*4096; }
    else       { Yop = X;
                 Z   = apow + ((size_t)layer*4 + s)*4096; }

    __shared__ float lx[64*68];
    __shared__ float ly[64*68];
    int tid = threadIdx.x;
    for (int e = tid; e < 4096; e += 256) {
        int r = e >> 6, c = e & 63;
        lx[r*68 + c] = X[e];
        ly[r*68 + c] = Yop[e];
    }
    __syncthreads();
    int r0 = (tid >> 4) << 2;
    int c0 = (tid & 15) << 2;
    float acc[4][4] = {};
    for (int k = 0; k < 64; k++) {
        float a0 = lx[(r0+0)*68 + k];
        float a1 = lx[(r0+1)*68 + k];
        float a2 = lx[(r0+2)*68 + k];
        float a3 = lx[(r0+3)*68 + k];
        f32x4 bv = *(const f32x4*)&ly[k*68 + c0];
        #pragma unroll
        for (int j = 0; j < 4; j++) {
            acc[0][j] += a0*bv[j]; acc[1][j] += a1*bv[j];
            acc[2][j] += a2*bv[j]; acc[3][j] += a3*bv[j];
        }
    }
    #pragma unroll
    for (int i2 = 0; i2 < 4; i2++) {
        f32x4 o; o[0]=acc[i2][0]; o[1]=acc[i2][1]; o[2]=acc[i2][2]; o[3]=acc[i2][3];
        *(f32x4*)&Z[(size_t)(r0+i2)*64 + c0] = o;
    }
}

// ---- castK: Kf32[i][j][n][m] -> f16 KbufT[i][n][(15-j)*64+m] ---------------
__global__ __launch_bounds__(256) void castK(const float* __restrict__ kf32,
                                             h16* __restrict__ kt)
{
    int idx = blockIdx.x*256 + threadIdx.x;
    const int total = LYR*NO*KD;     // 2,097,152
    for (; idx < total; idx += gridDim.x*256) {
        int i   = idx >> 16;
        int rem = idx & 65535;
        int n   = rem >> 10;
        int kap = rem & 1023;
        int jp  = kap >> 6, m = kap & 63;
        int j   = JT-1-jp;
        kt[idx] = (h16)kf32[(((size_t)i*JT + j)*64 + n)*64 + m];
    }
}

// ---- stage_mega: persistent systolic wavefront over (layer, time) ----------
__global__ __launch_bounds__(256, 1) void stage_mega(
    h16* pall, const h16* __restrict__ kt, int* cnt)
{
    __shared__ __align__(16) char smraw[2*32*68*4];   // 17,408 B (union)
    h16*   win = (h16*)smraw;                         // 48 x 72 h16
    float* red = (float*)smraw;                       // 2 x 32x68 f32
    int tid = threadIdx.x;
    int layer = blockIdx.x >> 3;
    int s8    = blockIdx.x & 7;
    int wv = tid >> 6, lane = tid & 63, r = lane & 15, q = lane >> 4;

    // ---- preload this layer's FIR bank into registers (128 VGPRs) ----------
    const h16* bbase = kt + (size_t)layer*NO*KD + (size_t)r*KD + wv*256 + q*8;
    h16x8 B[4][8];
    #pragma unroll
    for (int c = 0; c < 4; c++)
        #pragma unroll
        for (int ls = 0; ls < 8; ls++)
            B[c][ls] = *(const h16x8*)(bbase + c*(16*KD) + ls*32);

    const h16* pin  = pall + (size_t)layer*PBUF;
    h16*       pout = pall + (size_t)(layer+1)*PBUF;
    int* mycnt  = cnt + layer*NCH;
    int* depcnt = cnt + (layer-1)*NCH;

    for (int c = 0; c < NCH; c++) {
        size_t t0 = (size_t)c*CHUNK + s8*32;
        // wait for producer chunk (layer-1, c)
        if (layer > 0) {
            if (tid == 0) {
                while (__hip_atomic_load(&depcnt[c], __ATOMIC_ACQUIRE,
                                         __HIP_MEMORY_SCOPE_AGENT) < 8)
                    __builtin_amdgcn_s_sleep(2);
            }
        }
        __syncthreads();   // joins spin; also protects red->win overwrite

        // win[rr] = x_{t0-16+rr}: padded rows [t0, t0+48)
        for (int e = tid; e < 48*8; e += 256) {
            int rr = e >> 3, cc = e & 7;
            *(int4*)&win[rr*72 + cc*8] = *(const int4*)&pin[(t0 + rr)*64 + cc*8];
        }
        __syncthreads();

        // split-K4 chains: wave wv owns K in [wv*256, wv*256+256)
        const h16* abase = &win[(r + wv*4)*72 + q*8];
#define LDA(s, ls) (*(const h16x8*)(abase + ((s)*16 + ((ls)>>1))*72 + ((ls)&1)*32))
        f32x4 acc[2][4] = {};
        #pragma unroll
        for (int ls = 0; ls < 8; ls++) {
            h16x8 a0 = LDA(0, ls);
            h16x8 a1 = LDA(1, ls);
            #pragma unroll
            for (int cc = 0; cc < 4; cc++) {
                acc[0][cc] = __builtin_amdgcn_mfma_f32_16x16x32_f16(a0, B[cc][ls], acc[0][cc], 0,0,0);
                acc[1][cc] = __builtin_amdgcn_mfma_f32_16x16x32_f16(a1, B[cc][ls], acc[1][cc], 0,0,0);
            }
        }
#undef LDA
        __syncthreads();             // win dead; red may overwrite
        if (wv >= 2) {
            float* myred = red + (size_t)(wv-2)*(32*68);
            #pragma unroll
            for (int s = 0; s < 2; s++)
                #pragma unroll
                for (int cc = 0; cc < 4; cc++)
                    #pragma unroll
                    for (int g = 0; g < 4; g++)
                        myred[(s*16 + q*4 + g)*68 + cc*16 + r] = acc[s][cc][g];
        }
        __syncthreads();
        if (wv < 2) {
            float* myred = red + (size_t)wv*(32*68);
            #pragma unroll
            for (int s = 0; s < 2; s++)
                #pragma unroll
                for (int cc = 0; cc < 4; cc++)
                    #pragma unroll
                    for (int g = 0; g < 4; g++)
                        myred[(s*16 + q*4 + g)*68 + cc*16 + r] += acc[s][cc][g];
        }
        __syncthreads();
        {
            int orow = tid >> 3, cb2 = (tid & 7) << 3;
            f32x4 u0 = *(const f32x4*)&red[orow*68 + cb2];
            f32x4 u1 = *(const f32x4*)&red[orow*68 + cb2 + 4];
            f32x4 v0 = *(const f32x4*)&red[32*68 + orow*68 + cb2];
            f32x4 v1 = *(const f32x4*)&red[32*68 + orow*68 + cb2 + 4];
            u0 += v0; u1 += v1;
            h16 ov[8];
            #pragma unroll
            for (int j = 0; j < 4; j++) { ov[j] = (h16)u0[j]; ov[4+j] = (h16)u1[j]; }
            *(int4*)&pout[(JT + t0 + orow)*64 + cb2] = *(int4*)&ov[0];
        }
        // publish: make stores agent-visible, then bump counter (release)
        __threadfence();
        __syncthreads();
        if (tid == 0)
            __hip_atomic_fetch_add(&mycnt[c], 1, __ATOMIC_RELEASE,
                                   __HIP_MEMORY_SCOPE_AGENT);
    }
}

// ---- y_final: Y = sum_i X^(i) C_i^T, 32-row tiles, split layers 4-ways -----
__global__ __launch_bounds__(256, 2) void y_final(
    const h16* __restrict__ pall, const h16* __restrict__ ccast,
    float* __restrict__ out)
{
    __shared__ __align__(16) float red[2*32*68];
    int tid = threadIdx.x;
    size_t t0 = (size_t)blockIdx.x * 32;
    int wv = tid >> 6, lane = tid & 63, r = lane & 15, q = lane >> 4;
    const h16* abase = pall + (size_t)(wv*8 + 1)*PBUF + (JT + t0 + r)*64 + q*8;
    const h16* bbase = ccast + (size_t)(wv*8)*4096 + (size_t)r*64 + q*8;
#define LDA2(s, ls) (*(const h16x8*)(abase + (size_t)((ls)>>1)*PBUF + (s)*(16*64) + ((ls)&1)*32))
#define LDB2(c, ls) (*(const h16x8*)(bbase + ((ls)>>1)*4096 + (c)*(16*64) + ((ls)&1)*32))
    f32x4 acc[2][4] = {};
    h16x8 a0[2], b0[4], a1[2], b1[4];
    #pragma unroll
    for (int s = 0; s < 2; s++) { a0[s]=LDA2(s,0); a1[s]=LDA2(s,1); }
    #pragma unroll
    for (int c = 0; c < 4; c++) { b0[c]=LDB2(c,0); b1[c]=LDB2(c,1); }
    #pragma unroll 1
    for (int h2 = 0; h2 < 8; h2++) {
        int pE = 2*h2 + 2; pE = pE > 15 ? 15 : pE;
        int pO = 2*h2 + 3; pO = pO > 15 ? 15 : pO;
        h16x8 ca[2], cb[4];
        #pragma unroll
        for (int s = 0; s < 2; s++) ca[s] = a0[s];
        #pragma unroll
        for (int c = 0; c < 4; c++) cb[c] = b0[c];
        #pragma unroll
        for (int s = 0; s < 2; s++) a0[s] = LDA2(s, pE);
        #pragma unroll
        for (int c = 0; c < 4; c++) b0[c] = LDB2(c, pE);
        #pragma unroll
        for (int s = 0; s < 2; s++)
            #pragma unroll
            for (int c = 0; c < 4; c++)
                acc[s][c] = __builtin_amdgcn_mfma_f32_16x16x32_f16(ca[s], cb[c], acc[s][c], 0,0,0);
        #pragma unroll
        for (int s = 0; s < 2; s++) ca[s] = a1[s];
        #pragma unroll
        for (int c = 0; c < 4; c++) cb[c] = b1[c];
        #pragma unroll
        for (int s = 0; s < 2; s++) a1[s] = LDA2(s, pO);
        #pragma unroll
        for (int c = 0; c < 4; c++) b1[c] = LDB2(c, pO);
        #pragma unroll
        for (int s = 0; s < 2; s++)
            #pragma unroll
            for (int c = 0; c < 4; c++)
                acc[s][c] = __builtin_amdgcn_mfma_f32_16x16x32_f16(ca[s], cb[c], acc[s][c], 0,0,0);
    }
#undef LDA2
#undef LDB2
    if (wv >= 2) {
        float* myred = red + (size_t)(wv-2)*(32*68);
        #pragma unroll
        for (int s = 0; s < 2; s++)
            #pragma unroll
            for (int c = 0; c < 4; c++)
                #pragma unroll
                for (int g = 0; g < 4; g++)
                    myred[(s*16 + q*4 + g)*68 + c*16 + r] = acc[s][c][g];
    }
    __syncthreads();
    if (wv < 2) {
        float* myred = red + (size_t)wv*(32*68);
        #pragma unroll
        for (int s = 0; s < 2; s++)
            #pragma unroll
            for (int c = 0; c < 4; c++)
                #pragma unroll
                for (int g = 0; g < 4; g++)
                    myred[(s*16 + q*4 + g)*68 + c*16 + r] += acc[s][c][g];
    }
    __syncthreads();
    int orow = tid >> 3, cb2 = (tid & 7) << 3;
    f32x4 u0 = *(const f32x4*)&red[orow*68 + cb2];
    f32x4 u1 = *(const f32x4*)&red[orow*68 + cb2 + 4];
    f32x4 v0 = *(const f32x4*)&red[32*68 + orow*68 + cb2];
    f32x4 v1 = *(const f32x4*)&red[32*68 + orow*68 + cb2 + 4];
    u0 += v0; u1 += v1;
    size_t obase = (t0 + orow)*64 + cb2;
    *(f32x4*)&out[obase]     = u0;
    *(f32x4*)&out[obase + 4] = u1;
}

extern "C" void kernel_launch(void* const* d_in, const int* in_sizes, int n_in,
                              void* d_out, int out_size, void* d_ws, size_t ws_size,
                              hipStream_t stream)
{
    const float* u   = (const float*)d_in[0];
    const float* Ast = (const float*)d_in[1];
    const float* B0  = (const float*)d_in[2];
    const float* Bl  = (const float*)d_in[3];
    const float* Cst = (const float*)d_in[4];
    float* out = (float*)d_out;
    (void)in_sizes; (void)n_in; (void)out_size; (void)ws_size;

    char* ws = (char*)d_ws;
    const size_t PBUF_BYTES = PBUF*sizeof(h16);            // 1,050,624
    h16*   pall  = (h16*)ws;                               // 33 buffers
    h16*   ccast = (h16*)(ws + 33*PBUF_BYTES);             // 256 KiB
    h16*   kt    = (h16*)(ws + 33*PBUF_BYTES + 262144);    // 4 MiB
    float* kf32  = (float*)(ws + 33*PBUF_BYTES + 262144 + 4194304);   // 8 MiB
    float* apow  = (float*)(ws + 33*PBUF_BYTES + 262144 + 4194304 + 8388608); // 2 MiB
    int*   cnt   = (int*)(ws + 33*PBUF_BYTES + 262144 + 4194304 + 8388608 + 2097152); // 4 KiB

    prep1<<<2048, 256, 0, stream>>>(u, B0, Bl, Cst, pall, ccast, kf32, cnt);
    for (int s = 0; s < 4; s++) {
        int h = 1 << s;
        int grid = 32*(h + (s < 3 ? 1 : 0));
        build_step<<<grid, 256, 0, stream>>>(Ast, kf32, apow, s);
    }
    castK<<<2048, 256, 0, stream>>>(kf32, kt);
    stage_mega<<<256, 256, 0, stream>>>(pall, kt, cnt);
    y_final<<<TSEQ/32, 256, 0, stream>>>(pall, ccast, out);
}

// Round 7
// 466.058 us; speedup vs baseline: 2.8662x; 2.8662x over previous
//
#include <hip/hip_runtime.h>

// HierarchicalLTI2: 32-layer cascade of 64-dim LTI blocks, T=8192.
// Per-layer FIR truncation at J=16 taps; layer = GEMM (M=8192,N=64,K=1024)
// via implicit im2col, f16 MFMA fp32-acc. Taps built in fp32 by log-doubling.
// R7: back to serial stages (R6 megakernel's cross-XCD handoff cost ~20us/step
// -> structural dead end). Stage kernel rebuilt for latency:
//   - grid 512 x 16-row tiles -> 2 blocks/CU (2 waves/SIMD TLP)
//   - A-fragments direct from global (L1-cached reuse), no LDS staging leg
//   - full B bank preloaded into 128 VGPRs, 32 straight-line MFMAs
//   - castK folded into prep1/build_step (taps emitted in f16-T layout)

#define LYR 32
#define NO  64
#define TSEQ 8192
#define JT  16
#define KD  (JT*NO)               // 1024
#define PROWS (TSEQ+JT)           // 8208
#define PBUF ((size_t)PROWS*NO)   // 525312 elements (f16)

typedef _Float16 h16;
typedef _Float16 h16x8 __attribute__((ext_vector_type(8)));
typedef float    f32x4 __attribute__((ext_vector_type(4)));

// ---- prep1: zero pads (all 33 buffers), cast u + C, seed K_0 (fp32 + f16T) -
__global__ __launch_bounds__(256) void prep1(
    const float* __restrict__ u, const float* __restrict__ B0,
    const float* __restrict__ Bl, const float* __restrict__ Cst,
    h16* __restrict__ pall, h16* __restrict__ ccast, float* __restrict__ kf32,
    h16* __restrict__ kt)
{
    int idx = blockIdx.x*256 + threadIdx.x;
    const int n_pad0 = JT*NO;            // 1024
    const int n_u    = TSEQ*NO;          // 524288
    const int n_c    = LYR*NO*NO;        // 131072
    const int n_k    = LYR*NO*NO;        // 131072
    const int n_zp   = 32*JT*NO;         // 32768 (pads of buffers 1..32)
    int total = n_pad0 + n_u + n_c + n_k + n_zp;
    for (; idx < total; idx += gridDim.x*256) {
        int e = idx;
        if (e < n_pad0) { pall[e] = (h16)0.f; continue; }
        e -= n_pad0;
        if (e < n_u) { pall[n_pad0 + e] = (h16)u[e]; continue; }
        e -= n_u;
        if (e < n_c) { ccast[e] = (h16)Cst[e]; continue; }
        e -= n_c;
        if (e < n_k) {
            int i = e >> 12;
            int rr = e & 4095;
            float v = (i == 0) ? B0[rr] : Bl[e - 4096];
            kf32[((size_t)i*JT)*4096 + rr] = v;
            // f16 transposed-tap copy: tap j=0 -> jp = JT-1
            int n = rr >> 6, m = rr & 63;
            kt[((size_t)i*64 + n)*1024 + (JT-1)*64 + m] = (h16)v;
            continue;
        }
        e -= n_k;
        int b = e >> 10;                 // 0..31 -> buffer b+1
        int off = e & 1023;
        pall[(size_t)(b+1)*PBUF + off] = (h16)0.f;
    }
}

// ---- build_step: K_{h+q} = A^h * K_q ; A^{2h} = A^h * A^h (s=0..3) ---------
// Also emits new taps into kt in f16 transposed layout (jp = 15-j).
__global__ __launch_bounds__(256) void build_step(
    const float* __restrict__ A_stack, float* __restrict__ kf32,
    float* __restrict__ apow, h16* __restrict__ kt, int s)
{
    int h = 1 << s;
    int extra = (s < 3) ? 1 : 0;
    int slots = h + extra;
    int layer = blockIdx.x / slots;
    int q     = blockIdx.x % slots;
    const float* X = (s == 0) ? (A_stack + (size_t)layer*4096)
                              : (apow + ((size_t)layer*4 + (s-1))*4096);
    const float* Yop;
    float* Z;
    if (q < h) { Yop = kf32 + ((size_t)layer*JT + q)*4096;
                 Z   = kf32 + ((size_t)layer*JT + h + q)*4096; }
    else       { Yop = X;
                 Z   = apow + ((size_t)layer*4 + s)*4096; }

    __shared__ float lx[64*68];
    __shared__ float ly[64*68];
    int tid = threadIdx.x;
    for (int e = tid; e < 4096; e += 256) {
        int r = e >> 6, c = e & 63;
        lx[r*68 + c] = X[e];
        ly[r*68 + c] = Yop[e];
    }
    __syncthreads();
    int r0 = (tid >> 4) << 2;
    int c0 = (tid & 15) << 2;
    float acc[4][4] = {};
    for (int k = 0; k < 64; k++) {
        float a0 = lx[(r0+0)*68 + k];
        float a1 = lx[(r0+1)*68 + k];
        float a2 = lx[(r0+2)*68 + k];
        float a3 = lx[(r0+3)*68 + k];
        f32x4 bv = *(const f32x4*)&ly[k*68 + c0];
        #pragma unroll
        for (int j = 0; j < 4; j++) {
            acc[0][j] += a0*bv[j]; acc[1][j] += a1*bv[j];
            acc[2][j] += a2*bv[j]; acc[3][j] += a3*bv[j];
        }
    }
    int jp = (q < h) ? (JT-1 - (h + q)) : 0;
    #pragma unroll
    for (int i2 = 0; i2 < 4; i2++) {
        f32x4 o; o[0]=acc[i2][0]; o[1]=acc[i2][1]; o[2]=acc[i2][2]; o[3]=acc[i2][3];
        *(f32x4*)&Z[(size_t)(r0+i2)*64 + c0] = o;
        if (q < h) {
            h16 hv[4];
            #pragma unroll
            for (int j = 0; j < 4; j++) hv[j] = (h16)o[j];
            *(int2*)&kt[((size_t)layer*64 + r0+i2)*1024 + jp*64 + c0] = *(int2*)&hv[0];
        }
    }
}

// ---- stage16: one layer, grid 512 x 16-row tiles, split-K4, B in VGPRs -----
__global__ __launch_bounds__(256, 2) void stage16(
    const h16* __restrict__ pin, h16* __restrict__ pout,
    const h16* __restrict__ kb)
{
    __shared__ __align__(16) float red[2*16*68];   // 8704 B
    int tid = threadIdx.x;
    int wv = tid >> 6, lane = tid & 63, r = lane & 15, q = lane >> 4;
    size_t t0 = (size_t)blockIdx.x * 16;

    // B preload: wave wv owns K in [wv*256, wv*256+256) -> 32 frags, 128 VGPR
    const h16* bb = kb + (size_t)r*KD + wv*256 + q*8;
    h16x8 B[4][8];
    #pragma unroll
    for (int c = 0; c < 4; c++)
        #pragma unroll
        for (int ks = 0; ks < 8; ks++)
            B[c][ks] = *(const h16x8*)(bb + (size_t)c*(16*KD) + ks*32);

    // A direct from global: padded row t0 + r + jp, jp = wv*4 + (ks>>1),
    // col m = (ks&1)*32 + q*8   (output time t = t0+r reads x_{t-16+jp})
    const h16* ab = pin + (t0 + r + wv*4)*64 + q*8;
    h16x8 A[8];
    #pragma unroll
    for (int ks = 0; ks < 8; ks++)
        A[ks] = *(const h16x8*)(ab + (ks >> 1)*64 + (ks & 1)*32);

    f32x4 acc[4] = {};
    #pragma unroll
    for (int ks = 0; ks < 8; ks++)
        #pragma unroll
        for (int c = 0; c < 4; c++)
            acc[c] = __builtin_amdgcn_mfma_f32_16x16x32_f16(A[ks], B[c][ks], acc[c], 0,0,0);

    // reduce 4 wave-partials (2-copy scheme)
    if (wv >= 2) {
        float* m0 = red + (size_t)(wv-2)*(16*68);
        #pragma unroll
        for (int c = 0; c < 4; c++)
            #pragma unroll
            for (int g = 0; g < 4; g++)
                m0[(q*4 + g)*68 + c*16 + r] = acc[c][g];
    }
    __syncthreads();
    if (wv < 2) {
        float* m0 = red + (size_t)wv*(16*68);
        #pragma unroll
        for (int c = 0; c < 4; c++)
            #pragma unroll
            for (int g = 0; g < 4; g++)
                m0[(q*4 + g)*68 + c*16 + r] += acc[c][g];
    }
    __syncthreads();
    if (tid < 128) {
        int orow = tid >> 3, cb = (tid & 7) << 3;
        f32x4 u0 = *(const f32x4*)&red[orow*68 + cb];
        f32x4 u1 = *(const f32x4*)&red[orow*68 + cb + 4];
        f32x4 v0 = *(const f32x4*)&red[16*68 + orow*68 + cb];
        f32x4 v1 = *(const f32x4*)&red[16*68 + orow*68 + cb + 4];
        u0 += v0; u1 += v1;
        h16 ov[8];
        #pragma unroll
        for (int j = 0; j < 4; j++) { ov[j] = (h16)u0[j]; ov[4+j] = (h16)u1[j]; }
        *(int4*)&pout[(JT + t0 + orow)*64 + cb] = *(int4*)&ov[0];
    }
}

// ---- y_final: Y = sum_i X^(i) C_i^T, grid 512 x 16-row tiles, split-K4 -----
__global__ __launch_bounds__(256, 2) void y_final(
    const h16* __restrict__ pall, const h16* __restrict__ ccast,
    float* __restrict__ out)
{
    __shared__ __align__(16) float red[2*16*68];
    int tid = threadIdx.x;
    size_t t0 = (size_t)blockIdx.x * 16;
    int wv = tid >> 6, lane = tid & 63, r = lane & 15, q = lane >> 4;
    // wave wv owns layers [wv*8, wv*8+8): 16 k-steps of 32
    const h16* abase = pall + (size_t)(wv*8 + 1)*PBUF + (JT + t0 + r)*64 + q*8;
    const h16* bbase = ccast + (size_t)(wv*8)*4096 + (size_t)r*64 + q*8;
#define LDA2(ls) (*(const h16x8*)(abase + (size_t)((ls)>>1)*PBUF + ((ls)&1)*32))
#define LDB2(c, ls) (*(const h16x8*)(bbase + ((ls)>>1)*4096 + (c)*1024 + ((ls)&1)*32))
    f32x4 acc[4] = {};
    h16x8 a0, b0[4], a1, b1[4];
    a0 = LDA2(0); a1 = LDA2(1);
    #pragma unroll
    for (int c = 0; c < 4; c++) { b0[c] = LDB2(c,0); b1[c] = LDB2(c,1); }
    #pragma unroll 1
    for (int h2 = 0; h2 < 8; h2++) {
        int pE = 2*h2 + 2; pE = pE > 15 ? 15 : pE;
        int pO = 2*h2 + 3; pO = pO > 15 ? 15 : pO;
        h16x8 ca = a0, cb[4];
        #pragma unroll
        for (int c = 0; c < 4; c++) cb[c] = b0[c];
        a0 = LDA2(pE);
        #pragma unroll
        for (int c = 0; c < 4; c++) b0[c] = LDB2(c, pE);
        #pragma unroll
        for (int c = 0; c < 4; c++)
            acc[c] = __builtin_amdgcn_mfma_f32_16x16x32_f16(ca, cb[c], acc[c], 0,0,0);
        ca = a1;
        #pragma unroll
        for (int c = 0; c < 4; c++) cb[c] = b1[c];
        a1 = LDA2(pO);
        #pragma unroll
        for (int c = 0; c < 4; c++) b1[c] = LDB2(c, pO);
        #pragma unroll
        for (int c = 0; c < 4; c++)
            acc[c] = __builtin_amdgcn_mfma_f32_16x16x32_f16(ca, cb[c], acc[c], 0,0,0);
    }
#undef LDA2
#undef LDB2
    if (wv >= 2) {
        float* m0 = red + (size_t)(wv-2)*(16*68);
        #pragma unroll
        for (int c = 0; c < 4; c++)
            #pragma unroll
            for (int g = 0; g < 4; g++)
                m0[(q*4 + g)*68 + c*16 + r] = acc[c][g];
    }
    __syncthreads();
    if (wv < 2) {
        float* m0 = red + (size_t)wv*(16*68);
        #pragma unroll
        for (int c = 0; c < 4; c++)
            #pragma unroll
            for (int g = 0; g < 4; g++)
                m0[(q*4 + g)*68 + c*16 + r] += acc[c][g];
    }
    __syncthreads();
    {
        int orow = tid >> 4, cb = (tid & 15) << 2;
        f32x4 s0 = *(const f32x4*)&red[orow*68 + cb];
        f32x4 s1 = *(const f32x4*)&red[16*68 + orow*68 + cb];
        s0 += s1;
        *(f32x4*)&out[(t0 + orow)*64 + cb] = s0;
    }
}

extern "C" void kernel_launch(void* const* d_in, const int* in_sizes, int n_in,
                              void* d_out, int out_size, void* d_ws, size_t ws_size,
                              hipStream_t stream)
{
    const float* u   = (const float*)d_in[0];
    const float* Ast = (const float*)d_in[1];
    const float* B0  = (const float*)d_in[2];
    const float* Bl  = (const float*)d_in[3];
    const float* Cst = (const float*)d_in[4];
    float* out = (float*)d_out;
    (void)in_sizes; (void)n_in; (void)out_size; (void)ws_size;

    char* ws = (char*)d_ws;
    const size_t PBUF_BYTES = PBUF*sizeof(h16);            // 1,050,624
    h16*   pall  = (h16*)ws;                               // 33 buffers
    h16*   ccast = (h16*)(ws + 33*PBUF_BYTES);             // 256 KiB
    h16*   kt    = (h16*)(ws + 33*PBUF_BYTES + 262144);    // 4 MiB
    float* kf32  = (float*)(ws + 33*PBUF_BYTES + 262144 + 4194304);   // 8 MiB
    float* apow  = (float*)(ws + 33*PBUF_BYTES + 262144 + 4194304 + 8388608); // 2 MiB

    prep1<<<2048, 256, 0, stream>>>(u, B0, Bl, Cst, pall, ccast, kf32, kt);
    for (int s = 0; s < 4; s++) {
        int h = 1 << s;
        int grid = 32*(h + (s < 3 ? 1 : 0));
        build_step<<<grid, 256, 0, stream>>>(Ast, kf32, apow, kt, s);
    }
    for (int i = 0; i < LYR; i++) {
        stage16<<<TSEQ/16, 256, 0, stream>>>(pall + (size_t)i*PBUF,
                                             pall + (size_t)(i+1)*PBUF,
                                             kt + (size_t)i*NO*KD);
    }
    y_final<<<TSEQ/16, 256, 0, stream>>>(pall, ccast, out);
}